// Round 1
// baseline (728.398 us; speedup 1.0000x reference)
//
#include <hip/hip_runtime.h>
#include <math.h>

typedef __bf16 bf16_t;
typedef __attribute__((ext_vector_type(8))) __bf16 bf16x8;
typedef __attribute__((ext_vector_type(4))) __bf16 bf16x4;
typedef __attribute__((ext_vector_type(4))) float f32x4;

#define NTOK 4096   // B*L tokens
#define DDIM 1024
#define FDIM 4096
#define NEXP 8
#define CAP  4096   // per-expert token capacity (worst case)
#define HROWS (2*NTOK + 128)  // exact pair count + tail slack

// async 16B global->LDS. LDS dest must be wave-uniform base + lane*16 — our
// staging mapping (lds off = tid*16B) satisfies this per wave.
#define GLOAD_LDS16(g, l) \
  __builtin_amdgcn_global_load_lds((__attribute__((address_space(1))) void*)(g), \
                                   (__attribute__((address_space(3))) void*)(l), 16, 0, 0)

// ---------------------------------------------------------------- utilities
__global__ __launch_bounds__(256) void zero_kernel(float4* __restrict__ out4, int n4,
                                                   int* __restrict__ cnts) {
  int i = blockIdx.x * 256 + threadIdx.x;
  if (i < n4) out4[i] = make_float4(0.f, 0.f, 0.f, 0.f);
  if (i < NEXP) cnts[i] = 0;
}

__global__ __launch_bounds__(256) void cvt_x_kernel(const float4* __restrict__ in,
                                                    bf16x4* __restrict__ outp, int n4) {
  int i = blockIdx.x * 256 + threadIdx.x;
  if (i < n4) {
    float4 v = in[i];
    bf16x4 o;
    o.x = (bf16_t)v.x; o.y = (bf16_t)v.y; o.z = (bf16_t)v.z; o.w = (bf16_t)v.w;
    outp[i] = o;
  }
}

// per-expert transpose + fp32->bf16: in (E,R,C) -> out (E,C,R)
__global__ __launch_bounds__(256) void transpose_cvt(const float* __restrict__ in,
                                                     bf16_t* __restrict__ outp,
                                                     int R, int C) {
  __shared__ float tile[32][33];  // +1 pad: no bank conflicts
  int e = blockIdx.z;
  const float* ip = in + (size_t)e * R * C;
  bf16_t* op = outp + (size_t)e * R * C;
  int c0 = blockIdx.x * 32, r0 = blockIdx.y * 32;
  int tx = threadIdx.x & 31, ty = threadIdx.x >> 5;  // 32x8
#pragma unroll
  for (int i = 0; i < 4; i++)
    tile[ty + i * 8][tx] = ip[(size_t)(r0 + ty + i * 8) * C + c0 + tx];
  __syncthreads();
#pragma unroll
  for (int i = 0; i < 4; i++)
    op[(size_t)(c0 + ty + i * 8) * R + r0 + tx] = (bf16_t)tile[tx][ty + i * 8];
}

// ---------------------------------------------------------------- router
// one wave per token; fp64 logit accumulation so ranking vs numpy ref is stable
__global__ __launch_bounds__(256) void router_kernel(const float* __restrict__ x,
                                                     const float* __restrict__ Wg,
                                                     int* __restrict__ tokL,
                                                     float* __restrict__ gateL,
                                                     int* __restrict__ cnts) {
  int wid = threadIdx.x >> 6, lane = threadIdx.x & 63;
  int n = blockIdx.x * 4 + wid;
  const float* xr = x + (size_t)n * DDIM;
  double acc[NEXP];
#pragma unroll
  for (int e = 0; e < NEXP; e++) acc[e] = 0.0;
  for (int i = 0; i < DDIM / 64; i++) {
    int d = i * 64 + lane;
    float xv = xr[d];
    const float* wr = Wg + (size_t)d * NEXP;
#pragma unroll
    for (int e = 0; e < NEXP; e++) acc[e] += (double)xv * (double)wr[e];
  }
#pragma unroll
  for (int e = 0; e < NEXP; e++) {
    double v = acc[e];
#pragma unroll
    for (int off = 32; off; off >>= 1) v += __shfl_xor(v, off);
    acc[e] = v;
  }
  if (lane == 0) {
    int i1 = -1, i2 = -1;
    double s1 = -1e300, s2 = -1e300;
#pragma unroll
    for (int e = 0; e < NEXP; e++) {
      double v = acc[e];
      if (v > s1) { s2 = s1; i2 = i1; s1 = v; i1 = e; }
      else if (v > s2) { s2 = v; i2 = e; }
    }
    float g1 = 1.0f / (1.0f + expf((float)(-s1)));
    float g2 = 1.0f / (1.0f + expf((float)(-s2)));
    int p1 = atomicAdd(&cnts[i1], 1);
    tokL[i1 * CAP + p1] = n; gateL[i1 * CAP + p1] = g1;
    int p2 = atomicAdd(&cnts[i2], 1);
    tokL[i2 * CAP + p2] = n; gateL[i2 * CAP + p2] = g2;
  }
}

__global__ void offs_kernel(const int* __restrict__ cnts, int* __restrict__ offs) {
  if (threadIdx.x == 0) {
    int s = 0;
    for (int e = 0; e < NEXP; e++) { offs[e] = s; s += cnts[e]; }
    offs[NEXP] = s;
  }
}

// ---------------------------------------------------------------- GEMM1
// H[offs[e]+r, :] = gelu_tanh( x[tok[e][r], :] @ W1[e] + b1[e] ), bf16
// A: gathered xbf rows (M x 1024), B: wt1[e] = W1[e]^T (4096 x 1024, K-contig)
__global__ __launch_bounds__(256) void gemm1_kernel(
    const bf16_t* __restrict__ xbf, const bf16_t* __restrict__ wt1,
    const float* __restrict__ b1, const int* __restrict__ tokL,
    const int* __restrict__ cnts, const int* __restrict__ offs,
    bf16_t* __restrict__ H) {
  const int e = blockIdx.z;
  const int cnt = cnts[e];
  const int m0 = blockIdx.y * 128;
  if (m0 >= cnt) return;
  const int n0 = blockIdx.x * 128;
  const int t = threadIdx.x;

  __shared__ alignas(16) bf16_t As[128 * 32];
  __shared__ alignas(16) bf16_t Bs[128 * 32];

  const int sr = t >> 2;          // staging row 0..63
  const int sc = (t & 3) * 8;     // staging k-chunk
  const int r0 = m0 + sr, r1 = m0 + sr + 64;
  const int tok0 = (r0 < cnt) ? tokL[e * CAP + r0] : 0;
  const int tok1 = (r1 < cnt) ? tokL[e * CAP + r1] : 0;
  const bf16_t* gA0 = xbf + (size_t)tok0 * DDIM + sc;
  const bf16_t* gA1 = xbf + (size_t)tok1 * DDIM + sc;
  const bf16_t* wte = wt1 + (size_t)e * FDIM * DDIM;
  const bf16_t* gB0 = wte + (size_t)(n0 + sr) * DDIM + sc;
  const bf16_t* gB1 = wte + (size_t)(n0 + sr + 64) * DDIM + sc;
  bf16_t* lA0 = As + t * 8; bf16_t* lA1 = As + 2048 + t * 8;
  bf16_t* lB0 = Bs + t * 8; bf16_t* lB1 = Bs + 2048 + t * 8;

  const int lane = t & 63, w = t >> 6;
  const int wm = (w >> 1) * 64, wn = (w & 1) * 64;
  const int lid = lane & 15, quad = lane >> 4;

  f32x4 acc[4][4] = {};
  for (int kk = 0; kk < DDIM; kk += 32) {
    GLOAD_LDS16(gA0 + kk, lA0);
    GLOAD_LDS16(gA1 + kk, lA1);
    GLOAD_LDS16(gB0 + kk, lB0);
    GLOAD_LDS16(gB1 + kk, lB1);
    __syncthreads();
    bf16x8 af[4], bfm[4];
#pragma unroll
    for (int i = 0; i < 4; i++)
      af[i] = *(const bf16x8*)(As + (wm + i * 16 + lid) * 32 + quad * 8);
#pragma unroll
    for (int j = 0; j < 4; j++)
      bfm[j] = *(const bf16x8*)(Bs + (wn + j * 16 + lid) * 32 + quad * 8);
#pragma unroll
    for (int i = 0; i < 4; i++)
#pragma unroll
      for (int j = 0; j < 4; j++)
        acc[i][j] = __builtin_amdgcn_mfma_f32_16x16x32_bf16(af[i], bfm[j], acc[i][j], 0, 0, 0);
    __syncthreads();
  }

  const float* b1e = b1 + (size_t)e * FDIM;
  const int offe = offs[e];
#pragma unroll
  for (int i = 0; i < 4; i++) {
#pragma unroll
    for (int reg = 0; reg < 4; reg++) {
      int pos = m0 + wm + i * 16 + quad * 4 + reg;
      if (pos >= cnt) continue;  // never write pad rows (would race next expert)
      size_t hrow = (size_t)(offe + pos);
#pragma unroll
      for (int j = 0; j < 4; j++) {
        int col = n0 + wn + j * 16 + lid;
        float v = acc[i][j][reg] + b1e[col];
        float u = 0.7978845608028654f * (v + 0.044715f * v * v * v);
        float g = 0.5f * v * (1.0f + tanhf(u));
        H[hrow * FDIM + col] = (bf16_t)g;
      }
    }
  }
}

// ---------------------------------------------------------------- GEMM2
// out[tok,:] += gate * ( H[row,:] @ W2[e] + b2[e] )
// A: H rows (M x 4096), B: wt2[e] = W2[e]^T (1024 x 4096, K-contig)
__global__ __launch_bounds__(256) void gemm2_kernel(
    const bf16_t* __restrict__ H, const bf16_t* __restrict__ wt2,
    const float* __restrict__ b2, const int* __restrict__ tokL,
    const float* __restrict__ gateL, const int* __restrict__ cnts,
    const int* __restrict__ offs, float* __restrict__ out) {
  const int e = blockIdx.z;
  const int cnt = cnts[e];
  const int m0 = blockIdx.y * 128;
  if (m0 >= cnt) return;
  const int n0 = blockIdx.x * 128;
  const int t = threadIdx.x;
  const int offe = offs[e];

  __shared__ alignas(16) bf16_t As[128 * 32];
  __shared__ alignas(16) bf16_t Bs[128 * 32];

  const int sr = t >> 2;
  const int sc = (t & 3) * 8;
  // pad rows beyond cnt read next expert's H (or 0xAA slack) — finite, gated to 0
  const bf16_t* gA0 = H + (size_t)(offe + m0 + sr) * FDIM + sc;
  const bf16_t* gA1 = H + (size_t)(offe + m0 + sr + 64) * FDIM + sc;
  const bf16_t* wte = wt2 + (size_t)e * DDIM * FDIM;
  const bf16_t* gB0 = wte + (size_t)(n0 + sr) * FDIM + sc;
  const bf16_t* gB1 = wte + (size_t)(n0 + sr + 64) * FDIM + sc;
  bf16_t* lA0 = As + t * 8; bf16_t* lA1 = As + 2048 + t * 8;
  bf16_t* lB0 = Bs + t * 8; bf16_t* lB1 = Bs + 2048 + t * 8;

  const int lane = t & 63, w = t >> 6;
  const int wm = (w >> 1) * 64, wn = (w & 1) * 64;
  const int lid = lane & 15, quad = lane >> 4;

  f32x4 acc[4][4] = {};
  for (int kk = 0; kk < FDIM; kk += 32) {
    GLOAD_LDS16(gA0 + kk, lA0);
    GLOAD_LDS16(gA1 + kk, lA1);
    GLOAD_LDS16(gB0 + kk, lB0);
    GLOAD_LDS16(gB1 + kk, lB1);
    __syncthreads();
    bf16x8 af[4], bfm[4];
#pragma unroll
    for (int i = 0; i < 4; i++)
      af[i] = *(const bf16x8*)(As + (wm + i * 16 + lid) * 32 + quad * 8);
#pragma unroll
    for (int j = 0; j < 4; j++)
      bfm[j] = *(const bf16x8*)(Bs + (wn + j * 16 + lid) * 32 + quad * 8);
#pragma unroll
    for (int i = 0; i < 4; i++)
#pragma unroll
      for (int j = 0; j < 4; j++)
        acc[i][j] = __builtin_amdgcn_mfma_f32_16x16x32_bf16(af[i], bfm[j], acc[i][j], 0, 0, 0);
    __syncthreads();
  }

  const float* b2e = b2 + (size_t)e * DDIM;
#pragma unroll
  for (int i = 0; i < 4; i++) {
#pragma unroll
    for (int reg = 0; reg < 4; reg++) {
      int pos = m0 + wm + i * 16 + quad * 4 + reg;
      if (pos >= cnt) continue;
      int tok = tokL[e * CAP + pos];
      float gate = gateL[e * CAP + pos];
#pragma unroll
      for (int j = 0; j < 4; j++) {
        int col = n0 + wn + j * 16 + lid;
        float v = acc[i][j][reg] + b2e[col];
        atomicAdd(out + (size_t)tok * DDIM + col, gate * v);
      }
    }
  }
}

// ---------------------------------------------------------------- launch
extern "C" void kernel_launch(void* const* d_in, const int* in_sizes, int n_in,
                              void* d_out, int out_size, void* d_ws, size_t ws_size,
                              hipStream_t stream) {
  const float* x  = (const float*)d_in[0];
  const float* Wg = (const float*)d_in[1];
  const float* W1 = (const float*)d_in[2];
  const float* b1 = (const float*)d_in[3];
  const float* W2 = (const float*)d_in[4];
  const float* b2 = (const float*)d_in[5];
  float* out = (float*)d_out;

  char* ws = (char*)d_ws;
  size_t off = 0;
  auto alloc = [&](size_t bytes) -> void* {
    void* p = (void*)(ws + off);
    off += (bytes + 255) & ~(size_t)255;
    return p;
  };
  bf16_t* xbf   = (bf16_t*)alloc((size_t)NTOK * DDIM * 2);
  bf16_t* wt1   = (bf16_t*)alloc((size_t)NEXP * FDIM * DDIM * 2);
  bf16_t* wt2   = (bf16_t*)alloc((size_t)NEXP * DDIM * FDIM * 2);
  bf16_t* H     = (bf16_t*)alloc((size_t)HROWS * FDIM * 2);
  int*    tokL  = (int*)alloc((size_t)NEXP * CAP * 4);
  float*  gateL = (float*)alloc((size_t)NEXP * CAP * 4);
  int*    cnts  = (int*)alloc(64);
  int*    offs  = (int*)alloc(64);
  if (off > ws_size) return;  // workspace too small — fail loudly via wrong output

  const int n4 = NTOK * DDIM / 4;
  zero_kernel<<<(n4 + 255) / 256, 256, 0, stream>>>((float4*)out, n4, cnts);
  cvt_x_kernel<<<(n4 + 255) / 256, 256, 0, stream>>>((const float4*)x, (bf16x4*)xbf, n4);
  transpose_cvt<<<dim3(FDIM / 32, DDIM / 32, NEXP), 256, 0, stream>>>(W1, wt1, DDIM, FDIM);
  transpose_cvt<<<dim3(DDIM / 32, FDIM / 32, NEXP), 256, 0, stream>>>(W2, wt2, FDIM, DDIM);
  router_kernel<<<NTOK / 4, 256, 0, stream>>>(x, Wg, tokL, gateL, cnts);
  offs_kernel<<<1, 64, 0, stream>>>(cnts, offs);
  gemm1_kernel<<<dim3(FDIM / 128, CAP / 128, NEXP), 256, 0, stream>>>(
      xbf, wt1, b1, tokL, cnts, offs, H);
  gemm2_kernel<<<dim3(DDIM / 128, CAP / 128, NEXP), 256, 0, stream>>>(
      H, wt2, b2, tokL, gateL, cnts, offs, out);
}